// Round 2
// baseline (392.049 us; speedup 1.0000x reference)
//
#include <hip/hip_runtime.h>
#include <hip/hip_bf16.h>
#include <type_traits>

typedef __bf16 bf16_t;
typedef __bf16 v8bf __attribute__((ext_vector_type(8)));
typedef float  v4f  __attribute__((ext_vector_type(4)));

#define MFMA16(a, b, c) __builtin_amdgcn_mfma_f32_16x16x32_bf16((a), (b), (c), 0, 0, 0)

// Problem constants
#define B_SZ   2
#define SEQ    2048
#define DM     1024
#define NH     16
#define HD     64
#define M_TOT  4096   // B*S

// ---------------------------------------------------------------------------
// GEMM: C[M=4096, N=1024] = A[M,K=1024] @ W[K,N] + bias[N]
// A: fp32 (x) or bf16 (attention out). W,bias: fp32. Staged to bf16 in LDS.
// BM=128, BN=64, BK=32.  256 threads = 4 waves in 2x2, wave tile 64x32.
// MODE 0: out fp32 row-major [M][N]           (final projection -> d_out)
// MODE 1: out bf16 as [B, H, S, hd]           (Q, K)
// MODE 3: out bf16 as [B, H, hd, S]           (V transposed)
// ---------------------------------------------------------------------------
template <typename AT, int MODE>
__global__ __launch_bounds__(256)
void gemm_kernel(const AT* __restrict__ A, const float* __restrict__ W,
                 const float* __restrict__ bias, void* __restrict__ outv)
{
    // padded stride 40 elems (80 B, 16B-aligned rows; frag reads <=2-way conflicts)
    __shared__ __align__(16) bf16_t As[128 * 40];
    __shared__ __align__(16) bf16_t Bs[64 * 40];   // transposed: Bs[n][k]

    const int tid  = threadIdx.x;
    const int lane = tid & 63;
    const int wave = tid >> 6;
    const int wm   = (wave >> 1) * 64;   // wave row origin in block tile
    const int wn   = (wave & 1) * 32;    // wave col origin
    const int quad = lane >> 4;
    const int l15  = lane & 15;
    const int m0   = blockIdx.y * 128;
    const int n0   = blockIdx.x * 64;

    const v4f vzero = {0.f, 0.f, 0.f, 0.f};
    v4f acc[4][2];
#pragma unroll
    for (int mt = 0; mt < 4; ++mt)
#pragma unroll
        for (int nt = 0; nt < 2; ++nt) acc[mt][nt] = vzero;

    for (int it = 0; it < 32; ++it) {
        const int k0 = it * 32;
        // ---- stage A tile 128x32 (bf16 in LDS) ----
        if constexpr (std::is_same_v<AT, float>) {
            // 4096 floats = 1024 float4 chunks, 4 per thread
#pragma unroll
            for (int i = 0; i < 4; ++i) {
                int c = tid + i * 256;
                int row = c >> 3, q4 = c & 7;      // k offset = q4*4
                float4 v = *reinterpret_cast<const float4*>(
                    A + (size_t)(m0 + row) * DM + k0 + q4 * 4);
                union { bf16_t h[4]; int2 i2; } u;
                u.h[0] = (bf16_t)v.x; u.h[1] = (bf16_t)v.y;
                u.h[2] = (bf16_t)v.z; u.h[3] = (bf16_t)v.w;
                *reinterpret_cast<int2*>(&As[row * 40 + q4 * 4]) = u.i2;
            }
        } else {
            // bf16 A: 512 x 16B chunks, 2 per thread
#pragma unroll
            for (int i = 0; i < 2; ++i) {
                int c   = tid + i * 256;
                int row = c >> 2, koct = c & 3;
                int4 v = *reinterpret_cast<const int4*>(
                    A + (size_t)(m0 + row) * DM + k0 + koct * 8);
                *reinterpret_cast<int4*>(&As[row * 40 + koct * 8]) = v;
            }
        }
        // ---- stage W tile 32x64 -> transposed Bs[n][k] (fp32 -> bf16) ----
        // 2048 floats = 512 float4 chunks, 2 per thread
#pragma unroll
        for (int i = 0; i < 2; ++i) {
            int c = tid + i * 256;
            int kr = c >> 4, n4 = c & 15;          // n offset = n4*4
            float4 v = *reinterpret_cast<const float4*>(
                W + (size_t)(k0 + kr) * DM + n0 + n4 * 4);
            Bs[(n4 * 4 + 0) * 40 + kr] = (bf16_t)v.x;
            Bs[(n4 * 4 + 1) * 40 + kr] = (bf16_t)v.y;
            Bs[(n4 * 4 + 2) * 40 + kr] = (bf16_t)v.z;
            Bs[(n4 * 4 + 3) * 40 + kr] = (bf16_t)v.w;
        }
        __syncthreads();

        v8bf af[4], bfr[2];
#pragma unroll
        for (int mt = 0; mt < 4; ++mt)
            af[mt] = *reinterpret_cast<const v8bf*>(&As[(wm + mt * 16 + l15) * 40 + quad * 8]);
#pragma unroll
        for (int nt = 0; nt < 2; ++nt)
            bfr[nt] = *reinterpret_cast<const v8bf*>(&Bs[(wn + nt * 16 + l15) * 40 + quad * 8]);
#pragma unroll
        for (int mt = 0; mt < 4; ++mt)
#pragma unroll
            for (int nt = 0; nt < 2; ++nt)
                acc[mt][nt] = MFMA16(af[mt], bfr[nt], acc[mt][nt]);
        __syncthreads();
    }

    // epilogue: C/D layout col = lane&15, row = quad*4 + r
#pragma unroll
    for (int mt = 0; mt < 4; ++mt) {
#pragma unroll
        for (int nt = 0; nt < 2; ++nt) {
            int col = n0 + wn + nt * 16 + l15;
            float bv = bias[col];
#pragma unroll
            for (int r = 0; r < 4; ++r) {
                int row = m0 + wm + mt * 16 + quad * 4 + r;
                float v = acc[mt][nt][r] + bv;
                if (MODE == 0) {
                    reinterpret_cast<float*>(outv)[(size_t)row * DM + col] = v;
                } else {
                    int b = row >> 11, s = row & 2047;
                    int h = col >> 6,  d = col & 63;
                    size_t idx;
                    if (MODE == 3)
                        idx = ((size_t)(b * NH + h) * HD + d) * SEQ + s;     // [B,H,hd,S]
                    else
                        idx = ((size_t)(b * NH + h) * SEQ + s) * HD + d;     // [B,H,S,hd]
                    reinterpret_cast<bf16_t*>(outv)[idx] = (bf16_t)v;
                }
            }
        }
    }
}

// ---------------------------------------------------------------------------
// Flash attention, causal.  One block = 128 q-rows of one (b,h); 4 waves,
// wave w owns q-rows [w*32, w*32+32).  Key tiles of 64.
// Q,K in [B,H,S,hd]; V in [B,H,hd,S]; out O in [B,S,D] (heads merged), bf16.
// ---------------------------------------------------------------------------
__global__ __launch_bounds__(256)
void attn_kernel(const bf16_t* __restrict__ Q, const bf16_t* __restrict__ K,
                 const bf16_t* __restrict__ Vt, bf16_t* __restrict__ O)
{
    // QPs holds the Q tile; after q-frags are register-resident it is reused
    // for the P tile.  Each wave only touches its own 32 rows of QPs for P,
    // and it read exactly those rows for its q-frags, so no extra barrier.
    __shared__ __align__(16) bf16_t QPs[128 * 72];
    __shared__ __align__(16) bf16_t Ks[64 * 72];
    __shared__ __align__(16) bf16_t Vs[64 * 72];   // Vs[d][key]

    const int tid  = threadIdx.x;
    const int lane = tid & 63;
    const int w    = tid >> 6;
    const int quad = lane >> 4;
    const int l15  = lane & 15;
    const int qt   = blockIdx.x;         // q tile (128 rows)
    const int bh   = blockIdx.y;         // b*NH + h
    const int q0   = qt * 128;
    const size_t base = (size_t)bh * SEQ * HD;   // same for Q,K and (hd*S) Vt

    const bf16_t* Qg = Q  + base;
    const bf16_t* Kg = K  + base;
    const bf16_t* Vg = Vt + base;

    // load Q tile 128x64 (1024 chunks, 4 per thread)
#pragma unroll
    for (int i = 0; i < 4; ++i) {
        int c = tid + i * 256;
        int row = c >> 3, oct = c & 7;
        int4 v = *reinterpret_cast<const int4*>(Qg + (size_t)(q0 + row) * HD + oct * 8);
        *reinterpret_cast<int4*>(&QPs[row * 72 + oct * 8]) = v;
    }
    __syncthreads();

    // q fragments: A-operand layout m=lane&15, k=quad*8+j
    v8bf qf[2][2];
#pragma unroll
    for (int mt = 0; mt < 2; ++mt)
#pragma unroll
        for (int ks = 0; ks < 2; ++ks)
            qf[mt][ks] = *reinterpret_cast<const v8bf*>(
                &QPs[(w * 32 + mt * 16 + l15) * 72 + ks * 32 + quad * 8]);

    const v4f vzero = {0.f, 0.f, 0.f, 0.f};
    v4f acc_o[2][4];
    float mrow[2][4], lrow[2][4];
#pragma unroll
    for (int mt = 0; mt < 2; ++mt) {
#pragma unroll
        for (int nt = 0; nt < 4; ++nt) acc_o[mt][nt] = vzero;
#pragma unroll
        for (int r = 0; r < 4; ++r) { mrow[mt][r] = -1e30f; lrow[mt][r] = 0.f; }
    }

    const float L2E = 1.4426950408889634f;
    const int nkt = 2 * qt + 2;          // key tiles of 64 covering keys <= q0+127

    for (int kt = 0; kt < nkt; ++kt) {
        const int kt0 = kt * 64;
        // stage K tile 64x64 and V tile 64(d)x64(key): 2 chunks each per thread
#pragma unroll
        for (int i = 0; i < 2; ++i) {
            int c = tid + i * 256;
            int row = c >> 3, oct = c & 7;
            int4 kv = *reinterpret_cast<const int4*>(Kg + (size_t)(kt0 + row) * HD + oct * 8);
            *reinterpret_cast<int4*>(&Ks[row * 72 + oct * 8]) = kv;
            int4 vv = *reinterpret_cast<const int4*>(Vg + (size_t)row * SEQ + kt0 + oct * 8);
            *reinterpret_cast<int4*>(&Vs[row * 72 + oct * 8]) = vv;
        }
        __syncthreads();

        // S = Q K^T  (B-operand: n=lane&15 -> key, k -> d; K row-major is B^T-contig)
        v4f s[2][4];
#pragma unroll
        for (int mt = 0; mt < 2; ++mt)
#pragma unroll
            for (int nt = 0; nt < 4; ++nt) s[mt][nt] = vzero;
#pragma unroll
        for (int ks = 0; ks < 2; ++ks) {
            v8bf kb[4];
#pragma unroll
            for (int nt = 0; nt < 4; ++nt)
                kb[nt] = *reinterpret_cast<const v8bf*>(
                    &Ks[(nt * 16 + l15) * 72 + ks * 32 + quad * 8]);
#pragma unroll
            for (int mt = 0; mt < 2; ++mt)
#pragma unroll
                for (int nt = 0; nt < 4; ++nt)
                    s[mt][nt] = MFMA16(qf[mt][ks], kb[nt], s[mt][nt]);
        }

        const bool diag = (kt >= 2 * qt);   // only last two tiles touch diagonal
#pragma unroll
        for (int mt = 0; mt < 2; ++mt) {
            float rm[4] = {-1e30f, -1e30f, -1e30f, -1e30f};
#pragma unroll
            for (int nt = 0; nt < 4; ++nt) {
#pragma unroll
                for (int r = 0; r < 4; ++r) {
                    float v = s[mt][nt][r] * 0.125f;   // 1/sqrt(64)
                    if (diag) {
                        int qg = q0 + w * 32 + mt * 16 + quad * 4 + r;
                        int kg = kt0 + nt * 16 + l15;
                        if (kg > qg) v = -1e30f;
                    }
                    s[mt][nt][r] = v;
                    rm[r] = fmaxf(rm[r], v);
                }
            }
#pragma unroll
            for (int r = 0; r < 4; ++r) {
                rm[r] = fmaxf(rm[r], __shfl_xor(rm[r], 1));
                rm[r] = fmaxf(rm[r], __shfl_xor(rm[r], 2));
                rm[r] = fmaxf(rm[r], __shfl_xor(rm[r], 4));
                rm[r] = fmaxf(rm[r], __shfl_xor(rm[r], 8));
            }
            float alpha[4], rs[4];
#pragma unroll
            for (int r = 0; r < 4; ++r) {
                float mn = fmaxf(mrow[mt][r], rm[r]);
                alpha[r] = exp2f((mrow[mt][r] - mn) * L2E);
                mrow[mt][r] = mn;
                rs[r] = 0.f;
            }
#pragma unroll
            for (int nt = 0; nt < 4; ++nt)
#pragma unroll
                for (int r = 0; r < 4; ++r) {
                    float p = exp2f((s[mt][nt][r] - mrow[mt][r]) * L2E);
                    s[mt][nt][r] = p;
                    rs[r] += p;
                }
#pragma unroll
            for (int r = 0; r < 4; ++r) {
                rs[r] += __shfl_xor(rs[r], 1);
                rs[r] += __shfl_xor(rs[r], 2);
                rs[r] += __shfl_xor(rs[r], 4);
                rs[r] += __shfl_xor(rs[r], 8);
                lrow[mt][r] = lrow[mt][r] * alpha[r] + rs[r];
            }
            // write P (bf16) into this wave's own rows of QPs; rescale O
#pragma unroll
            for (int nt = 0; nt < 4; ++nt) {
#pragma unroll
                for (int r = 0; r < 4; ++r)
                    QPs[(w * 32 + mt * 16 + quad * 4 + r) * 72 + nt * 16 + l15] =
                        (bf16_t)s[mt][nt][r];
#pragma unroll
                for (int r = 0; r < 4; ++r)
                    acc_o[mt][nt][r] *= alpha[r];
            }
        }
        // P rows are per-wave private; same-wave LDS write->read is ordered.

        // O += P V   (A = P from QPs; B-operand n=lane&15 -> d, k -> key; Vs[d][key])
#pragma unroll
        for (int ks = 0; ks < 2; ++ks) {
            v8bf pa[2], vb[4];
#pragma unroll
            for (int mt = 0; mt < 2; ++mt)
                pa[mt] = *reinterpret_cast<const v8bf*>(
                    &QPs[(w * 32 + mt * 16 + l15) * 72 + ks * 32 + quad * 8]);
#pragma unroll
            for (int nt = 0; nt < 4; ++nt)
                vb[nt] = *reinterpret_cast<const v8bf*>(
                    &Vs[(nt * 16 + l15) * 72 + ks * 32 + quad * 8]);
#pragma unroll
            for (int mt = 0; mt < 2; ++mt)
#pragma unroll
                for (int nt = 0; nt < 4; ++nt)
                    acc_o[mt][nt] = MFMA16(pa[mt], vb[nt], acc_o[mt][nt]);
        }
        __syncthreads();   // Ks/Vs consumed before next stage overwrites
    }

    // epilogue: O /= l, write [B,S,D] bf16 with heads merged
    const int bO = bh >> 4, hO = bh & 15;
#pragma unroll
    for (int mt = 0; mt < 2; ++mt)
#pragma unroll
        for (int nt = 0; nt < 4; ++nt)
#pragma unroll
            for (int r = 0; r < 4; ++r) {
                int row = q0 + w * 32 + mt * 16 + quad * 4 + r;
                int col = hO * HD + nt * 16 + l15;
                O[((size_t)bO * SEQ + row) * DM + col] =
                    (bf16_t)(acc_o[mt][nt][r] / lrow[mt][r]);
            }
}

// ---------------------------------------------------------------------------
extern "C" void kernel_launch(void* const* d_in, const int* in_sizes, int n_in,
                              void* d_out, int out_size, void* d_ws, size_t ws_size,
                              hipStream_t stream) {
    const float* x  = (const float*)d_in[0];
    const float* Wq = (const float*)d_in[1];
    const float* bq = (const float*)d_in[2];
    const float* Wk = (const float*)d_in[3];
    const float* bk = (const float*)d_in[4];
    const float* Wv = (const float*)d_in[5];
    const float* bv = (const float*)d_in[6];
    const float* Wo = (const float*)d_in[7];
    const float* bo = (const float*)d_in[8];

    bf16_t* ws = (bf16_t*)d_ws;
    bf16_t* Qb = ws;                       // [B,H,S,hd]  4M elems
    bf16_t* Kb = ws + 4194304;             // [B,H,S,hd]
    bf16_t* Vb = ws + 8388608;             // [B,H,hd,S]
    bf16_t* Ob = ws + 12582912;            // [B,S,D] bf16

    dim3 gg(16, 32), bb(256);
    gemm_kernel<float, 1><<<gg, bb, 0, stream>>>(x, Wq, bq, Qb);
    gemm_kernel<float, 1><<<gg, bb, 0, stream>>>(x, Wk, bk, Kb);
    gemm_kernel<float, 3><<<gg, bb, 0, stream>>>(x, Wv, bv, Vb);
    attn_kernel<<<dim3(16, 32), bb, 0, stream>>>(Qb, Kb, Vb, Ob);
    gemm_kernel<bf16_t, 0><<<gg, bb, 0, stream>>>(Ob, Wo, bo, (float*)d_out);
}

// Round 3
// 294.643 us; speedup vs baseline: 1.3306x; 1.3306x over previous
//
#include <hip/hip_runtime.h>
#include <hip/hip_bf16.h>

typedef __bf16 bf16_t;
typedef __bf16 v8bf __attribute__((ext_vector_type(8)));
typedef float  v4f  __attribute__((ext_vector_type(4)));

#define MFMA16(a, b, c) __builtin_amdgcn_mfma_f32_16x16x32_bf16((a), (b), (c), 0, 0, 0)

#define B_SZ   2
#define SEQ    2048
#define DM     1024
#define NH     16
#define HD     64
#define M_TOT  4096

// ---------------------------------------------------------------------------
// convert x fp32 -> bf16  (4M elems, 8/thread)
// ---------------------------------------------------------------------------
__global__ __launch_bounds__(256)
void conv_x_kernel(const float* __restrict__ src, bf16_t* __restrict__ dst)
{
    int i = (blockIdx.x * 256 + threadIdx.x) * 8;
    float4 a = *reinterpret_cast<const float4*>(src + i);
    float4 b = *reinterpret_cast<const float4*>(src + i + 4);
    union { bf16_t h[8]; int4 v; } u;
    u.h[0] = (bf16_t)a.x; u.h[1] = (bf16_t)a.y; u.h[2] = (bf16_t)a.z; u.h[3] = (bf16_t)a.w;
    u.h[4] = (bf16_t)b.x; u.h[5] = (bf16_t)b.y; u.h[6] = (bf16_t)b.z; u.h[7] = (bf16_t)b.w;
    *reinterpret_cast<int4*>(dst + i) = u.v;
}

// ---------------------------------------------------------------------------
// transpose+convert W fp32 [k][n] -> bf16 [n][k].  grid (32,32,4)
// ---------------------------------------------------------------------------
__global__ __launch_bounds__(256)
void conv_wt_kernel(const float* __restrict__ Wq, const float* __restrict__ Wk,
                    const float* __restrict__ Wv, const float* __restrict__ Wo,
                    bf16_t* __restrict__ WqkvT, bf16_t* __restrict__ WoT)
{
    __shared__ float t[32][33];
    const int z = blockIdx.z;
    const float* src = (z == 0) ? Wq : (z == 1) ? Wk : (z == 2) ? Wv : Wo;
    bf16_t* dst = (z < 3) ? (WqkvT + (size_t)z * 1048576) : WoT;
    const int tx = threadIdx.x & 31, ty = threadIdx.x >> 5;
    const int c0 = blockIdx.x * 32, r0 = blockIdx.y * 32;
#pragma unroll
    for (int i = 0; i < 4; ++i)
        t[ty + i * 8][tx] = src[(size_t)(r0 + ty + i * 8) * DM + c0 + tx];
    __syncthreads();
#pragma unroll
    for (int i = 0; i < 4; ++i)
        dst[(size_t)(c0 + ty + i * 8) * DM + r0 + tx] = (bf16_t)t[tx][ty + i * 8];
}

// ---------------------------------------------------------------------------
// GEMM, both operands bf16 k-contiguous: C[M][N] = A[M][K] @ BT[N][K]^T + bias
// BM=BN=128, BK=64.  256 thr, 4 waves 2x2, wave 64x64 (4x4 frags).
// MODE 1: fused QKV — blockIdx.x: mat=bx>>3, n0=(bx&7)*128.
//         mat0 -> Qb [B,H,S,hd] scaled by 0.125; mat1 -> Kb [B,H,S,hd];
//         mat2 -> Vb [B,H,hd,S].
// MODE 0: final projection, fp32 out row-major (oQ).
// ---------------------------------------------------------------------------
template <int MODE>
__global__ __launch_bounds__(256)
void gemm_bt_kernel(const bf16_t* __restrict__ A, const bf16_t* __restrict__ BT,
                    const float* __restrict__ b0, const float* __restrict__ b1,
                    const float* __restrict__ b2,
                    void* __restrict__ oQ, void* __restrict__ oK, void* __restrict__ oV)
{
    __shared__ __align__(16) bf16_t As[128 * 72];
    __shared__ __align__(16) bf16_t Bs[128 * 72];

    const int tid  = threadIdx.x;
    const int lane = tid & 63;
    const int wave = tid >> 6;
    const int wm   = (wave >> 1) * 64;
    const int wn   = (wave & 1) * 64;
    const int quad = lane >> 4;
    const int l15  = lane & 15;

    int mat, n0;
    const bf16_t* Bmat;
    if (MODE == 1) { mat = blockIdx.x >> 3; n0 = (blockIdx.x & 7) * 128;
                     Bmat = BT + (size_t)mat * 1048576; }
    else           { mat = 0; n0 = blockIdx.x * 128; Bmat = BT; }
    const int m0 = blockIdx.y * 128;

    const v4f vzero = {0.f, 0.f, 0.f, 0.f};
    v4f acc[4][4];
#pragma unroll
    for (int mt = 0; mt < 4; ++mt)
#pragma unroll
        for (int nt = 0; nt < 4; ++nt) acc[mt][nt] = vzero;

    for (int it = 0; it < 16; ++it) {
        const int k0 = it * 64;
        // stage A 128x64 and BT 128x64: 1024 int4 chunks each, 4/thread each
#pragma unroll
        for (int i = 0; i < 4; ++i) {
            int c = tid + i * 256;
            int row = c >> 3, ko = c & 7;
            *reinterpret_cast<int4*>(&As[row * 72 + ko * 8]) =
                *reinterpret_cast<const int4*>(A + (size_t)(m0 + row) * DM + k0 + ko * 8);
            *reinterpret_cast<int4*>(&Bs[row * 72 + ko * 8]) =
                *reinterpret_cast<const int4*>(Bmat + (size_t)(n0 + row) * DM + k0 + ko * 8);
        }
        __syncthreads();
#pragma unroll
        for (int ks = 0; ks < 2; ++ks) {
            v8bf af[4], bfq[4];
#pragma unroll
            for (int mt = 0; mt < 4; ++mt)
                af[mt] = *reinterpret_cast<const v8bf*>(
                    &As[(wm + mt * 16 + l15) * 72 + ks * 32 + quad * 8]);
#pragma unroll
            for (int nt = 0; nt < 4; ++nt)
                bfq[nt] = *reinterpret_cast<const v8bf*>(
                    &Bs[(wn + nt * 16 + l15) * 72 + ks * 32 + quad * 8]);
#pragma unroll
            for (int mt = 0; mt < 4; ++mt)
#pragma unroll
                for (int nt = 0; nt < 4; ++nt)
                    acc[mt][nt] = MFMA16(af[mt], bfq[nt], acc[mt][nt]);
        }
        __syncthreads();
    }

    const float* bias = (MODE == 1) ? (mat == 0 ? b0 : mat == 1 ? b1 : b2) : b0;
    const float scale = (MODE == 1 && mat == 0) ? 0.125f : 1.0f;
#pragma unroll
    for (int mt = 0; mt < 4; ++mt) {
#pragma unroll
        for (int nt = 0; nt < 4; ++nt) {
            int col = n0 + wn + nt * 16 + l15;
            float bv = bias[col];
#pragma unroll
            for (int r = 0; r < 4; ++r) {
                int row = m0 + wm + mt * 16 + quad * 4 + r;
                float v = (acc[mt][nt][r] + bv) * scale;
                if (MODE == 0) {
                    reinterpret_cast<float*>(oQ)[(size_t)row * DM + col] = v;
                } else {
                    int b = row >> 11, s = row & 2047;
                    int h = col >> 6,  d = col & 63;
                    if (mat == 2)
                        reinterpret_cast<bf16_t*>(oV)[((size_t)(b * NH + h) * HD + d) * SEQ + s] = (bf16_t)v;
                    else {
                        bf16_t* dst = (mat == 0) ? (bf16_t*)oQ : (bf16_t*)oK;
                        dst[((size_t)(b * NH + h) * SEQ + s) * HD + d] = (bf16_t)v;
                    }
                }
            }
        }
    }
}

// ---------------------------------------------------------------------------
// Flash attention, causal.  Block = 128 q-rows of one (b,h); wave w owns rows
// [w*32, w*32+32).  K/V double-buffered with register prefetch; one barrier
// per key tile.  Row-sum l folded into MFMA via a ones B-operand.
// Q pre-scaled by 1/8.  Q,K [B,H,S,hd]; V [B,H,hd,S]; O [B,S,D] bf16.
// ---------------------------------------------------------------------------
__global__ __launch_bounds__(256)
void attn_kernel(const bf16_t* __restrict__ Q, const bf16_t* __restrict__ K,
                 const bf16_t* __restrict__ Vt, bf16_t* __restrict__ O)
{
    __shared__ __align__(16) bf16_t QPs[128 * 72];
    __shared__ __align__(16) bf16_t Ks[2][64 * 72];
    __shared__ __align__(16) bf16_t Vs[2][64 * 72];

    const int tid  = threadIdx.x;
    const int lane = tid & 63;
    const int w    = tid >> 6;
    const int quad = lane >> 4;
    const int l15  = lane & 15;
    const int qt   = blockIdx.x;
    const int bh   = blockIdx.y;
    const int q0   = qt * 128;
    const size_t base = (size_t)bh * SEQ * HD;

    const bf16_t* Qg = Q  + base;
    const bf16_t* Kg = K  + base;
    const bf16_t* Vg = Vt + base;

#pragma unroll
    for (int i = 0; i < 4; ++i) {
        int c = tid + i * 256;
        int row = c >> 3, oct = c & 7;
        *reinterpret_cast<int4*>(&QPs[row * 72 + oct * 8]) =
            *reinterpret_cast<const int4*>(Qg + (size_t)(q0 + row) * HD + oct * 8);
    }
    __syncthreads();

    v8bf qf[2][2];
#pragma unroll
    for (int mt = 0; mt < 2; ++mt)
#pragma unroll
        for (int ks = 0; ks < 2; ++ks)
            qf[mt][ks] = *reinterpret_cast<const v8bf*>(
                &QPs[(w * 32 + mt * 16 + l15) * 72 + ks * 32 + quad * 8]);

    const v4f vzero = {0.f, 0.f, 0.f, 0.f};
    v4f acc_o[2][4], acc_l[2];
    float mrow[2][4];
#pragma unroll
    for (int mt = 0; mt < 2; ++mt) {
#pragma unroll
        for (int nt = 0; nt < 4; ++nt) acc_o[mt][nt] = vzero;
        acc_l[mt] = vzero;
#pragma unroll
        for (int r = 0; r < 4; ++r) mrow[mt][r] = -1e30f;
    }

    const bf16_t one = (bf16_t)1.0f;
    const v8bf ones = {one, one, one, one, one, one, one, one};
    const float L2E = 1.4426950408889634f;
    const int nkt = 2 * qt + 2;

    // prefetch tile 0
    int4 kreg[2], vreg[2];
#pragma unroll
    for (int i = 0; i < 2; ++i) {
        int c = tid + i * 256;
        int row = c >> 3, oct = c & 7;
        kreg[i] = *reinterpret_cast<const int4*>(Kg + (size_t)row * HD + oct * 8);
        vreg[i] = *reinterpret_cast<const int4*>(Vg + (size_t)row * SEQ + oct * 8);
    }

    for (int kt = 0; kt < nkt; ++kt) {
        const int cur = kt & 1;
        // commit prefetched tile to LDS buffer `cur`
#pragma unroll
        for (int i = 0; i < 2; ++i) {
            int c = tid + i * 256;
            int row = c >> 3, oct = c & 7;
            *reinterpret_cast<int4*>(&Ks[cur][row * 72 + oct * 8]) = kreg[i];
            *reinterpret_cast<int4*>(&Vs[cur][row * 72 + oct * 8]) = vreg[i];
        }
        // issue prefetch for tile kt+1 (hidden behind barrier + compute)
        if (kt + 1 < nkt) {
            const int nt0 = (kt + 1) * 64;
#pragma unroll
            for (int i = 0; i < 2; ++i) {
                int c = tid + i * 256;
                int row = c >> 3, oct = c & 7;
                kreg[i] = *reinterpret_cast<const int4*>(Kg + (size_t)(nt0 + row) * HD + oct * 8);
                vreg[i] = *reinterpret_cast<const int4*>(Vg + (size_t)row * SEQ + nt0 + oct * 8);
            }
        }
        __syncthreads();

        // S = Q K^T (Q pre-scaled)
        v4f s[2][4];
#pragma unroll
        for (int mt = 0; mt < 2; ++mt)
#pragma unroll
            for (int nt = 0; nt < 4; ++nt) s[mt][nt] = vzero;
#pragma unroll
        for (int ks = 0; ks < 2; ++ks) {
            v8bf kb[4];
#pragma unroll
            for (int nt = 0; nt < 4; ++nt)
                kb[nt] = *reinterpret_cast<const v8bf*>(
                    &Ks[cur][(nt * 16 + l15) * 72 + ks * 32 + quad * 8]);
#pragma unroll
            for (int mt = 0; mt < 2; ++mt)
#pragma unroll
                for (int nt = 0; nt < 4; ++nt)
                    s[mt][nt] = MFMA16(qf[mt][ks], kb[nt], s[mt][nt]);
        }

        const int kt0 = kt * 64;
        const bool diag = (kt >= 2 * qt);
#pragma unroll
        for (int mt = 0; mt < 2; ++mt) {
            float rm[4] = {-1e30f, -1e30f, -1e30f, -1e30f};
#pragma unroll
            for (int nt = 0; nt < 4; ++nt) {
#pragma unroll
                for (int r = 0; r < 4; ++r) {
                    float v = s[mt][nt][r];
                    if (diag) {
                        int qg = q0 + w * 32 + mt * 16 + quad * 4 + r;
                        int kg = kt0 + nt * 16 + l15;
                        if (kg > qg) v = -1e30f;
                    }
                    s[mt][nt][r] = v;
                    rm[r] = fmaxf(rm[r], v);
                }
            }
#pragma unroll
            for (int r = 0; r < 4; ++r) {
                rm[r] = fmaxf(rm[r], __shfl_xor(rm[r], 1));
                rm[r] = fmaxf(rm[r], __shfl_xor(rm[r], 2));
                rm[r] = fmaxf(rm[r], __shfl_xor(rm[r], 4));
                rm[r] = fmaxf(rm[r], __shfl_xor(rm[r], 8));
            }
            float alpha[4];
#pragma unroll
            for (int r = 0; r < 4; ++r) {
                float mn = fmaxf(mrow[mt][r], rm[r]);
                alpha[r] = exp2f((mrow[mt][r] - mn) * L2E);
                mrow[mt][r] = mn;
            }
#pragma unroll
            for (int nt = 0; nt < 4; ++nt)
#pragma unroll
                for (int r = 0; r < 4; ++r) {
                    float p = exp2f((s[mt][nt][r] - mrow[mt][r]) * L2E);
                    QPs[(w * 32 + mt * 16 + quad * 4 + r) * 72 + nt * 16 + l15] = (bf16_t)p;
                }
#pragma unroll
            for (int nt = 0; nt < 4; ++nt)
#pragma unroll
                for (int r = 0; r < 4; ++r)
                    acc_o[mt][nt][r] *= alpha[r];
#pragma unroll
            for (int r = 0; r < 4; ++r)
                acc_l[mt][r] *= alpha[r];
        }

        // O += P V ; l += P·1  (same-wave LDS round-trip, no barrier needed)
#pragma unroll
        for (int ks = 0; ks < 2; ++ks) {
            v8bf pa[2], vb[4];
#pragma unroll
            for (int mt = 0; mt < 2; ++mt)
                pa[mt] = *reinterpret_cast<const v8bf*>(
                    &QPs[(w * 32 + mt * 16 + l15) * 72 + ks * 32 + quad * 8]);
#pragma unroll
            for (int nt = 0; nt < 4; ++nt)
                vb[nt] = *reinterpret_cast<const v8bf*>(
                    &Vs[cur][(nt * 16 + l15) * 72 + ks * 32 + quad * 8]);
#pragma unroll
            for (int mt = 0; mt < 2; ++mt) {
                acc_l[mt] = MFMA16(pa[mt], ones, acc_l[mt]);
#pragma unroll
                for (int nt = 0; nt < 4; ++nt)
                    acc_o[mt][nt] = MFMA16(pa[mt], vb[nt], acc_o[mt][nt]);
            }
        }
    }

    const int bO = bh >> 4, hO = bh & 15;
#pragma unroll
    for (int mt = 0; mt < 2; ++mt)
#pragma unroll
        for (int nt = 0; nt < 4; ++nt)
#pragma unroll
            for (int r = 0; r < 4; ++r) {
                int row = q0 + w * 32 + mt * 16 + quad * 4 + r;
                int col = hO * HD + nt * 16 + l15;
                O[((size_t)bO * SEQ + row) * DM + col] =
                    (bf16_t)(acc_o[mt][nt][r] / acc_l[mt][r]);
            }
}

// ---------------------------------------------------------------------------
extern "C" void kernel_launch(void* const* d_in, const int* in_sizes, int n_in,
                              void* d_out, int out_size, void* d_ws, size_t ws_size,
                              hipStream_t stream) {
    const float* x  = (const float*)d_in[0];
    const float* Wq = (const float*)d_in[1];
    const float* bq = (const float*)d_in[2];
    const float* Wk = (const float*)d_in[3];
    const float* bk = (const float*)d_in[4];
    const float* Wv = (const float*)d_in[5];
    const float* bv = (const float*)d_in[6];
    const float* Wo = (const float*)d_in[7];
    const float* bo = (const float*)d_in[8];

    bf16_t* ws = (bf16_t*)d_ws;
    bf16_t* xb     = ws;                   // [4096,1024]        4M   (dead after QKV)
    bf16_t* WqkvT  = ws + 4194304;         // [3,1024n,1024k]    3M
    bf16_t* WoT    = ws + 7340032;         // [1024n,1024k]      1M
    bf16_t* Qb     = ws + 8388608;         // [B,H,S,hd]         4M   (pre-scaled 1/8)
    bf16_t* Kb     = ws + 12582912;        // [B,H,S,hd]         4M
    bf16_t* Vb     = ws + 16777216;        // [B,H,hd,S]         4M
    bf16_t* Ob     = ws;                   // [B,S,D]  aliases xb (stream-ordered safe)

    conv_x_kernel<<<2048, 256, 0, stream>>>(x, xb);
    conv_wt_kernel<<<dim3(32, 32, 4), 256, 0, stream>>>(Wq, Wk, Wv, Wo, WqkvT, WoT);
    gemm_bt_kernel<1><<<dim3(24, 32), 256, 0, stream>>>(xb, WqkvT, bq, bk, bv, Qb, Kb, Vb);
    attn_kernel<<<dim3(16, 32), 256, 0, stream>>>(Qb, Kb, Vb, Ob);
    gemm_bt_kernel<0><<<dim3(8, 32), 256, 0, stream>>>(Ob, WoT, bo, nullptr, nullptr,
                                                       d_out, nullptr, nullptr);
}

// Round 4
// 273.296 us; speedup vs baseline: 1.4345x; 1.0781x over previous
//
#include <hip/hip_runtime.h>
#include <hip/hip_bf16.h>

typedef __bf16 bf16_t;
typedef __bf16 v8bf __attribute__((ext_vector_type(8)));
typedef float  v4f  __attribute__((ext_vector_type(4)));

#define MFMA16(a, b, c) __builtin_amdgcn_mfma_f32_16x16x32_bf16((a), (b), (c), 0, 0, 0)

#define B_SZ   2
#define SEQ    2048
#define DM     1024
#define NH     16
#define HD     64
#define M_TOT  4096

// ---------------------------------------------------------------------------
// convert x fp32 -> bf16  (4M elems, 8/thread)
// ---------------------------------------------------------------------------
__global__ __launch_bounds__(256)
void conv_x_kernel(const float* __restrict__ src, bf16_t* __restrict__ dst)
{
    int i = (blockIdx.x * 256 + threadIdx.x) * 8;
    float4 a = *reinterpret_cast<const float4*>(src + i);
    float4 b = *reinterpret_cast<const float4*>(src + i + 4);
    union { bf16_t h[8]; int4 v; } u;
    u.h[0] = (bf16_t)a.x; u.h[1] = (bf16_t)a.y; u.h[2] = (bf16_t)a.z; u.h[3] = (bf16_t)a.w;
    u.h[4] = (bf16_t)b.x; u.h[5] = (bf16_t)b.y; u.h[6] = (bf16_t)b.z; u.h[7] = (bf16_t)b.w;
    *reinterpret_cast<int4*>(dst + i) = u.v;
}

// ---------------------------------------------------------------------------
// transpose+convert W fp32 [k][n] -> bf16 [n][k].  grid (32,32,4)
// ---------------------------------------------------------------------------
__global__ __launch_bounds__(256)
void conv_wt_kernel(const float* __restrict__ Wq, const float* __restrict__ Wk,
                    const float* __restrict__ Wv, const float* __restrict__ Wo,
                    bf16_t* __restrict__ WqkvT, bf16_t* __restrict__ WoT)
{
    __shared__ float t[32][33];
    const int z = blockIdx.z;
    const float* src = (z == 0) ? Wq : (z == 1) ? Wk : (z == 2) ? Wv : Wo;
    bf16_t* dst = (z < 3) ? (WqkvT + (size_t)z * 1048576) : WoT;
    const int tx = threadIdx.x & 31, ty = threadIdx.x >> 5;
    const int c0 = blockIdx.x * 32, r0 = blockIdx.y * 32;
#pragma unroll
    for (int i = 0; i < 4; ++i)
        t[ty + i * 8][tx] = src[(size_t)(r0 + ty + i * 8) * DM + c0 + tx];
    __syncthreads();
#pragma unroll
    for (int i = 0; i < 4; ++i)
        dst[(size_t)(c0 + ty + i * 8) * DM + r0 + tx] = (bf16_t)t[tx][ty + i * 8];
}

// ---------------------------------------------------------------------------
// GEMM, both operands bf16 k-contiguous: C[M][N] = A[M][K] @ BT[N][K]^T + bias
// BM=BN=128, BK=64.  256 thr, 4 waves 2x2, wave 64x64 (4x4 frags).
// MODE 1: fused QKV — mat=bx>>3, n0=(bx&7)*128; mat0->Qb scaled 1/8, mat1->Kb,
//         mat2->Vb transposed.  MODE 0: final projection, fp32 out.
// ---------------------------------------------------------------------------
template <int MODE>
__global__ __launch_bounds__(256)
void gemm_bt_kernel(const bf16_t* __restrict__ A, const bf16_t* __restrict__ BT,
                    const float* __restrict__ b0, const float* __restrict__ b1,
                    const float* __restrict__ b2,
                    void* __restrict__ oQ, void* __restrict__ oK, void* __restrict__ oV)
{
    __shared__ __align__(16) bf16_t As[128 * 72];
    __shared__ __align__(16) bf16_t Bs[128 * 72];

    const int tid  = threadIdx.x;
    const int lane = tid & 63;
    const int wave = tid >> 6;
    const int wm   = (wave >> 1) * 64;
    const int wn   = (wave & 1) * 64;
    const int quad = lane >> 4;
    const int l15  = lane & 15;

    int mat, n0;
    const bf16_t* Bmat;
    if (MODE == 1) { mat = blockIdx.x >> 3; n0 = (blockIdx.x & 7) * 128;
                     Bmat = BT + (size_t)mat * 1048576; }
    else           { mat = 0; n0 = blockIdx.x * 128; Bmat = BT; }
    const int m0 = blockIdx.y * 128;

    const v4f vzero = {0.f, 0.f, 0.f, 0.f};
    v4f acc[4][4];
#pragma unroll
    for (int mt = 0; mt < 4; ++mt)
#pragma unroll
        for (int nt = 0; nt < 4; ++nt) acc[mt][nt] = vzero;

    for (int it = 0; it < 16; ++it) {
        const int k0 = it * 64;
#pragma unroll
        for (int i = 0; i < 4; ++i) {
            int c = tid + i * 256;
            int row = c >> 3, ko = c & 7;
            *reinterpret_cast<int4*>(&As[row * 72 + ko * 8]) =
                *reinterpret_cast<const int4*>(A + (size_t)(m0 + row) * DM + k0 + ko * 8);
            *reinterpret_cast<int4*>(&Bs[row * 72 + ko * 8]) =
                *reinterpret_cast<const int4*>(Bmat + (size_t)(n0 + row) * DM + k0 + ko * 8);
        }
        __syncthreads();
#pragma unroll
        for (int ks = 0; ks < 2; ++ks) {
            v8bf af[4], bfq[4];
#pragma unroll
            for (int mt = 0; mt < 4; ++mt)
                af[mt] = *reinterpret_cast<const v8bf*>(
                    &As[(wm + mt * 16 + l15) * 72 + ks * 32 + quad * 8]);
#pragma unroll
            for (int nt = 0; nt < 4; ++nt)
                bfq[nt] = *reinterpret_cast<const v8bf*>(
                    &Bs[(wn + nt * 16 + l15) * 72 + ks * 32 + quad * 8]);
#pragma unroll
            for (int mt = 0; mt < 4; ++mt)
#pragma unroll
                for (int nt = 0; nt < 4; ++nt)
                    acc[mt][nt] = MFMA16(af[mt], bfq[nt], acc[mt][nt]);
        }
        __syncthreads();
    }

    const float* bias = (MODE == 1) ? (mat == 0 ? b0 : mat == 1 ? b1 : b2) : b0;
    const float scale = (MODE == 1 && mat == 0) ? 0.125f : 1.0f;
#pragma unroll
    for (int mt = 0; mt < 4; ++mt) {
#pragma unroll
        for (int nt = 0; nt < 4; ++nt) {
            int col = n0 + wn + nt * 16 + l15;
            float bv = bias[col];
#pragma unroll
            for (int r = 0; r < 4; ++r) {
                int row = m0 + wm + mt * 16 + quad * 4 + r;
                float v = (acc[mt][nt][r] + bv) * scale;
                if (MODE == 0) {
                    reinterpret_cast<float*>(oQ)[(size_t)row * DM + col] = v;
                } else {
                    int b = row >> 11, s = row & 2047;
                    int h = col >> 6,  d = col & 63;
                    if (mat == 2)
                        reinterpret_cast<bf16_t*>(oV)[((size_t)(b * NH + h) * HD + d) * SEQ + s] = (bf16_t)v;
                    else {
                        bf16_t* dst = (mat == 0) ? (bf16_t*)oQ : (bf16_t*)oK;
                        dst[((size_t)(b * NH + h) * SEQ + s) * HD + d] = (bf16_t)v;
                    }
                }
            }
        }
    }
}

// ---------------------------------------------------------------------------
// Flash attention, causal, S^T formulation.
// Block = 128 q-rows of one (b,h); wave w owns rows [w*32, w*32+32).
// qt swizzled so each CU's two resident blocks pair (qt, 15-qt) -> balanced.
// S^T = K Q^T : lane holds one q (=l15) per qtile, 16 keys in-lane
//   -> row max / row sum are in-lane + 2 shuffles (xor 16, 32).
// P^T written as packed ds_write_b64; O^T = V^T P^T; l computed in-lane.
// Q pre-scaled by 1/8.  Q,K [B,H,S,hd]; V [B,H,hd,S]; O [B,S,D] bf16.
// ---------------------------------------------------------------------------
__global__ __launch_bounds__(256)
void attn_kernel(const bf16_t* __restrict__ Q, const bf16_t* __restrict__ K,
                 const bf16_t* __restrict__ Vt, bf16_t* __restrict__ O)
{
    __shared__ __align__(16) bf16_t QPs[128 * 72];
    __shared__ __align__(16) bf16_t Ks[2][64 * 72];
    __shared__ __align__(16) bf16_t Vs[2][64 * 72];

    const int tid  = threadIdx.x;
    const int lane = tid & 63;
    const int w    = tid >> 6;
    const int quad = lane >> 4;
    const int l15  = lane & 15;
    const int bh   = blockIdx.y;
    const int qt   = (bh >= 16) ? (15 - (int)blockIdx.x) : (int)blockIdx.x;  // balance
    const int q0   = qt * 128;
    const size_t base = (size_t)bh * SEQ * HD;

    const bf16_t* Qg = Q  + base;
    const bf16_t* Kg = K  + base;
    const bf16_t* Vg = Vt + base;

#pragma unroll
    for (int i = 0; i < 4; ++i) {
        int c = tid + i * 256;
        int row = c >> 3, oct = c & 7;
        *reinterpret_cast<int4*>(&QPs[row * 72 + oct * 8]) =
            *reinterpret_cast<const int4*>(Qg + (size_t)(q0 + row) * HD + oct * 8);
    }
    __syncthreads();

    // q fragments (B-operand: n = q = l15, k = d = quad*8+j)
    v8bf qf[2][2];
#pragma unroll
    for (int qtile = 0; qtile < 2; ++qtile)
#pragma unroll
        for (int ks = 0; ks < 2; ++ks)
            qf[qtile][ks] = *reinterpret_cast<const v8bf*>(
                &QPs[(w * 32 + qtile * 16 + l15) * 72 + ks * 32 + quad * 8]);

    const v4f vzero = {0.f, 0.f, 0.f, 0.f};
    v4f acc_o[4][2];                 // [dtile][qtile]  O^T: row=d, col=q
    float mrow[2], lrow[2];
#pragma unroll
    for (int dt = 0; dt < 4; ++dt)
#pragma unroll
        for (int qtile = 0; qtile < 2; ++qtile) acc_o[dt][qtile] = vzero;
    mrow[0] = mrow[1] = -1e30f;
    lrow[0] = lrow[1] = 0.f;

    const float L2E = 1.4426950408889634f;
    const int nkt = 2 * qt + 2;

    // prefetch tile 0
    int4 kreg[2], vreg[2];
#pragma unroll
    for (int i = 0; i < 2; ++i) {
        int c = tid + i * 256;
        int row = c >> 3, oct = c & 7;
        kreg[i] = *reinterpret_cast<const int4*>(Kg + (size_t)row * HD + oct * 8);
        vreg[i] = *reinterpret_cast<const int4*>(Vg + (size_t)row * SEQ + oct * 8);
    }

    for (int kt = 0; kt < nkt; ++kt) {
        const int cur = kt & 1;
#pragma unroll
        for (int i = 0; i < 2; ++i) {
            int c = tid + i * 256;
            int row = c >> 3, oct = c & 7;
            *reinterpret_cast<int4*>(&Ks[cur][row * 72 + oct * 8]) = kreg[i];
            *reinterpret_cast<int4*>(&Vs[cur][row * 72 + oct * 8]) = vreg[i];
        }
        if (kt + 1 < nkt) {
            const int nt0 = (kt + 1) * 64;
#pragma unroll
            for (int i = 0; i < 2; ++i) {
                int c = tid + i * 256;
                int row = c >> 3, oct = c & 7;
                kreg[i] = *reinterpret_cast<const int4*>(Kg + (size_t)(nt0 + row) * HD + oct * 8);
                vreg[i] = *reinterpret_cast<const int4*>(Vg + (size_t)row * SEQ + nt0 + oct * 8);
            }
        }
        __syncthreads();

        // S^T = K Q^T  (A = K: m=key=l15, k=d; B = Q: n=q=l15, k=d)
        v4f st[4][2];
#pragma unroll
        for (int ktile = 0; ktile < 4; ++ktile)
#pragma unroll
            for (int qtile = 0; qtile < 2; ++qtile) st[ktile][qtile] = vzero;
#pragma unroll
        for (int ks = 0; ks < 2; ++ks) {
            v8bf kb[4];
#pragma unroll
            for (int ktile = 0; ktile < 4; ++ktile)
                kb[ktile] = *reinterpret_cast<const v8bf*>(
                    &Ks[cur][(ktile * 16 + l15) * 72 + ks * 32 + quad * 8]);
#pragma unroll
            for (int ktile = 0; ktile < 4; ++ktile)
#pragma unroll
                for (int qtile = 0; qtile < 2; ++qtile)
                    st[ktile][qtile] = MFMA16(kb[ktile], qf[qtile][ks], st[ktile][qtile]);
        }

        const int kt0 = kt * 64;
        const bool diag = (kt >= 2 * qt);
#pragma unroll
        for (int qtile = 0; qtile < 2; ++qtile) {
            const int qg = q0 + w * 32 + qtile * 16 + l15;   // this lane's q row
            float rm = -1e30f;
#pragma unroll
            for (int ktile = 0; ktile < 4; ++ktile)
#pragma unroll
                for (int r = 0; r < 4; ++r) {
                    float v = st[ktile][qtile][r];
                    if (diag) {
                        int kg = kt0 + ktile * 16 + quad * 4 + r;
                        if (kg > qg) v = -1e30f;
                    }
                    st[ktile][qtile][r] = v;
                    rm = fmaxf(rm, v);
                }
            rm = fmaxf(rm, __shfl_xor(rm, 16));
            rm = fmaxf(rm, __shfl_xor(rm, 32));
            float mn = fmaxf(mrow[qtile], rm);
            float alpha = exp2f((mrow[qtile] - mn) * L2E);
            mrow[qtile] = mn;
            float rs = 0.f;
#pragma unroll
            for (int ktile = 0; ktile < 4; ++ktile) {
                union { bf16_t h[4]; int2 v; } u;
#pragma unroll
                for (int r = 0; r < 4; ++r) {
                    float p = exp2f((st[ktile][qtile][r] - mn) * L2E);
                    rs += p;
                    u.h[r] = (bf16_t)p;
                }
                *reinterpret_cast<int2*>(
                    &QPs[(w * 32 + qtile * 16 + l15) * 72 + ktile * 16 + quad * 4]) = u.v;
            }
            rs += __shfl_xor(rs, 16);
            rs += __shfl_xor(rs, 32);
            lrow[qtile] = lrow[qtile] * alpha + rs;
#pragma unroll
            for (int dt = 0; dt < 4; ++dt)
#pragma unroll
                for (int r = 0; r < 4; ++r)
                    acc_o[dt][qtile][r] *= alpha;
        }

        // O^T += V^T P^T  (A = V^T: m=d=l15, k=key; B = P^T: n=q=l15, k=key)
#pragma unroll
        for (int ks = 0; ks < 2; ++ks) {
            v8bf vb[4], pf[2];
#pragma unroll
            for (int dt = 0; dt < 4; ++dt)
                vb[dt] = *reinterpret_cast<const v8bf*>(
                    &Vs[cur][(dt * 16 + l15) * 72 + ks * 32 + quad * 8]);
#pragma unroll
            for (int qtile = 0; qtile < 2; ++qtile)
                pf[qtile] = *reinterpret_cast<const v8bf*>(
                    &QPs[(w * 32 + qtile * 16 + l15) * 72 + ks * 32 + quad * 8]);
#pragma unroll
            for (int dt = 0; dt < 4; ++dt)
#pragma unroll
                for (int qtile = 0; qtile < 2; ++qtile)
                    acc_o[dt][qtile] = MFMA16(vb[dt], pf[qtile], acc_o[dt][qtile]);
        }
    }

    // epilogue: O^T lane holds q=l15 (col), d=quad*4+r (row) -> 4 d-contig bf16
    const int bO = bh >> 4, hO = bh & 15;
#pragma unroll
    for (int qtile = 0; qtile < 2; ++qtile) {
        float rinv = 1.f / lrow[qtile];
        int s = q0 + w * 32 + qtile * 16 + l15;
#pragma unroll
        for (int dt = 0; dt < 4; ++dt) {
            union { bf16_t h[4]; int2 v; } u;
#pragma unroll
            for (int r = 0; r < 4; ++r)
                u.h[r] = (bf16_t)(acc_o[dt][qtile][r] * rinv);
            *reinterpret_cast<int2*>(
                &O[((size_t)bO * SEQ + s) * DM + hO * 64 + dt * 16 + quad * 4]) = u.v;
        }
    }
}

// ---------------------------------------------------------------------------
extern "C" void kernel_launch(void* const* d_in, const int* in_sizes, int n_in,
                              void* d_out, int out_size, void* d_ws, size_t ws_size,
                              hipStream_t stream) {
    const float* x  = (const float*)d_in[0];
    const float* Wq = (const float*)d_in[1];
    const float* bq = (const float*)d_in[2];
    const float* Wk = (const float*)d_in[3];
    const float* bk = (const float*)d_in[4];
    const float* Wv = (const float*)d_in[5];
    const float* bv = (const float*)d_in[6];
    const float* Wo = (const float*)d_in[7];
    const float* bo = (const float*)d_in[8];

    bf16_t* ws = (bf16_t*)d_ws;
    bf16_t* xb     = ws;                   // [4096,1024]        4M   (dead after QKV)
    bf16_t* WqkvT  = ws + 4194304;         // [3,1024n,1024k]    3M
    bf16_t* WoT    = ws + 7340032;         // [1024n,1024k]      1M
    bf16_t* Qb     = ws + 8388608;         // [B,H,S,hd]         4M   (pre-scaled 1/8)
    bf16_t* Kb     = ws + 12582912;        // [B,H,S,hd]         4M
    bf16_t* Vb     = ws + 16777216;        // [B,H,hd,S]         4M
    bf16_t* Ob     = ws;                   // [B,S,D]  aliases xb (stream-ordered safe)

    conv_x_kernel<<<2048, 256, 0, stream>>>(x, xb);
    conv_wt_kernel<<<dim3(32, 32, 4), 256, 0, stream>>>(Wq, Wk, Wv, Wo, WqkvT, WoT);
    gemm_bt_kernel<1><<<dim3(24, 32), 256, 0, stream>>>(xb, WqkvT, bq, bk, bv, Qb, Kb, Vb);
    attn_kernel<<<dim3(16, 32), 256, 0, stream>>>(Qb, Kb, Vb, Ob);
    gemm_bt_kernel<0><<<dim3(8, 32), 256, 0, stream>>>(Ob, WoT, bo, nullptr, nullptr,
                                                       d_out, nullptr, nullptr);
}